// Round 3
// baseline (362.995 us; speedup 1.0000x reference)
//
#include <hip/hip_runtime.h>
#include <math.h>

#define XS 512
#define YS 512
#define WDIM 256
#define NCELLS (XS * YS)          // 262144
#define K1_BLOCKS 2048
#define K1_THREADS 256            // 4 waves/block, 32 cells/wave

typedef float vfloat4 __attribute__((ext_vector_type(4)));

// Kernel 1: per-cell squared L2 distance; batched-butterfly argmin.
// Each wave covers 32 cells in 8 batches of 4. Per batch, each lane keeps a
// partial sum for each of the 4 cells (its float4 k-slice), then a value-
// halving butterfly reduces all 4 cells at once:
//   masks {1,1,2}: 4 partials -> 1 value/lane, cell = base + (lane&3)
//   masks {4,8,16,32}: fold the 16 duplicate lane-groups
// => 7 cross-lane ops per 4 KB (1.75/cell) vs 6/cell before, and one
// compare/select per batch per lane instead of one per cell wave-wide.
__global__ __launch_bounds__(K1_THREADS) void som_dist_kernel(
    const float* __restrict__ x,
    const float* __restrict__ W,
    unsigned long long* __restrict__ ws) {
  const int lane = threadIdx.x & 63;
  const int waveInBlock = threadIdx.x >> 6;
  const int gw = blockIdx.x * (K1_THREADS / 64) + waveInBlock;

  const vfloat4 xv = ((const vfloat4*)x)[lane];

  float bestD = 3.4e38f;
  int bestI = 0;

  const int base = gw * 32;  // 32 consecutive cells per wave
  const int r3 = lane & 3;   // which cell of each batch this lane ends up owning

#pragma unroll 2
  for (int b = 0; b < 8; ++b) {
    const int cb = base + b * 4;
    const vfloat4* row = (const vfloat4*)(W + (size_t)cb * WDIM) + lane;
    // 4 independent coalesced 1 KB row reads (64 lanes x 16 B each)
    const vfloat4 w0 = row[0 * (WDIM / 4)];
    const vfloat4 w1 = row[1 * (WDIM / 4)];
    const vfloat4 w2 = row[2 * (WDIM / 4)];
    const vfloat4 w3 = row[3 * (WDIM / 4)];

    float d;
    float s0, s1, s2, s3;
    d = xv.x - w0.x; s0  = d * d;
    d = xv.y - w0.y; s0 += d * d;
    d = xv.z - w0.z; s0 += d * d;
    d = xv.w - w0.w; s0 += d * d;

    d = xv.x - w1.x; s1  = d * d;
    d = xv.y - w1.y; s1 += d * d;
    d = xv.z - w1.z; s1 += d * d;
    d = xv.w - w1.w; s1 += d * d;

    d = xv.x - w2.x; s2  = d * d;
    d = xv.y - w2.y; s2 += d * d;
    d = xv.z - w2.z; s2 += d * d;
    d = xv.w - w2.w; s2 += d * d;

    d = xv.x - w3.x; s3  = d * d;
    d = xv.y - w3.y; s3 += d * d;
    d = xv.z - w3.z; s3 += d * d;
    d = xv.w - w3.w; s3 += d * d;

    // stage mask=1: (s0,s1) and (s2,s3); lane bit0 picks which cell it keeps
    const bool b0 = (lane & 1) != 0;
    float keepA = b0 ? s1 : s0;
    float sendA = b0 ? s0 : s1;
    float t0 = keepA + __shfl_xor(sendA, 1, 64);   // cell (cb + b0)
    float keepB = b0 ? s3 : s2;
    float sendB = b0 ? s2 : s3;
    float t1 = keepB + __shfl_xor(sendB, 1, 64);   // cell (cb + 2 + b0)

    // stage mask=2: lane bit1 picks t0 vs t1
    const bool b1 = (lane & 2) != 0;
    float keepC = b1 ? t1 : t0;
    float sendC = b1 ? t0 : t1;
    float v = keepC + __shfl_xor(sendC, 2, 64);    // cell (cb + (lane&3)), 1/16 of sum

    // fold the 16 duplicate lane-groups (lane bits 2..5)
    v += __shfl_xor(v, 4, 64);
    v += __shfl_xor(v, 8, 64);
    v += __shfl_xor(v, 16, 64);
    v += __shfl_xor(v, 32, 64);

    // strict < keeps the lowest index on ties within this lane's residue class
    if (v < bestD) { bestD = v; bestI = cb + r3; }
  }

  // fp32 dist (>=0) bit pattern is order-monotone as u32; index in low 32.
  // Packed u64 min => lowest distance, ties broken by lowest index.
  unsigned long long packed =
      ((unsigned long long)__float_as_uint(bestD) << 32) | (unsigned int)bestI;

  // wave-level min across the 64 per-residue candidates
#pragma unroll
  for (int off = 32; off > 0; off >>= 1) {
    const unsigned long long o = __shfl_xor(packed, off, 64);
    packed = (o < packed) ? o : packed;
  }

  __shared__ unsigned long long sbest[K1_THREADS / 64];
  if (lane == 0) sbest[waveInBlock] = packed;
  __syncthreads();
  if (threadIdx.x == 0) {
    unsigned long long m = sbest[0];
#pragma unroll
    for (int i = 1; i < K1_THREADS / 64; ++i) {
      const unsigned long long v2 = sbest[i];
      m = (v2 < m) ? v2 : m;
    }
    atomicMin(ws, m);  // device-scope; 2048 total, uncontended
  }
}

// Kernel 2: broadcast-read the winner, write h; block 0 appends wx, wy.
__global__ __launch_bounds__(256) void som_h_kernel(
    const unsigned long long* __restrict__ ws,
    const int* __restrict__ time_step,
    float* __restrict__ out) {
  const int t = threadIdx.x;
  const unsigned long long packed = *ws;   // wave-uniform; L2-hot broadcast
  const int flat = (int)(packed & 0xFFFFFFFFULL);
  const int wx = flat >> 9;       // flat / 512
  const int wy = flat & (YS - 1); // flat % 512

  // decay = SIGMA * exp(-t / (1000/ln(SIGMA))), SIGMA = 2
  const float ts = (float)(*time_step);
  const float TIME_CONST = 1442.6950408889634f;  // 1000 / ln(2)
  const float decay = 2.0f * expf(-ts / TIME_CONST);
  const float denom = 2.0f * decay * decay;
  const float inv = -1.0f / denom;

  // h[i][j] = exp(-((i-wx)^2 + (j-wy)^2) / denom); one float4 per thread
  const int e = blockIdx.x * 1024 + t * 4;
  const int i = e >> 9;
  const int j0 = e & (YS - 1);
  const float di = (float)(i - wx);
  const float di2 = di * di;

  const float d0 = (float)(j0 + 0 - wy);
  const float d1 = (float)(j0 + 1 - wy);
  const float d2 = (float)(j0 + 2 - wy);
  const float d3 = (float)(j0 + 3 - wy);
  vfloat4 r;
  r.x = expf((di2 + d0 * d0) * inv);
  r.y = expf((di2 + d1 * d1) * inv);
  r.z = expf((di2 + d2 * d2) * inv);
  r.w = expf((di2 + d3 * d3) * inv);
  ((vfloat4*)out)[e >> 2] = r;

  if (blockIdx.x == 0 && t == 0) {
    out[NCELLS] = (float)wx;      // output order: h, wx, wy
    out[NCELLS + 1] = (float)wy;
  }
}

extern "C" void kernel_launch(void* const* d_in, const int* in_sizes, int n_in,
                              void* d_out, int out_size, void* d_ws, size_t ws_size,
                              hipStream_t stream) {
  const float* x = (const float*)d_in[0];
  const float* W = (const float*)d_in[1];
  const int* ts = (const int*)d_in[2];
  float* out = (float*)d_out;
  unsigned long long* ws = (unsigned long long*)d_ws;

  // ws[0] := 0xFFFFFFFFFFFFFFFF so atomicMin never depends on poison value.
  (void)hipMemsetAsync(ws, 0xFF, 8, stream);
  som_dist_kernel<<<K1_BLOCKS, K1_THREADS, 0, stream>>>(x, W, ws);
  som_h_kernel<<<NCELLS / 1024, 256, 0, stream>>>(ws, ts, out);
}

// Round 4
// 362.577 us; speedup vs baseline: 1.0012x; 1.0012x over previous
//
#include <hip/hip_runtime.h>
#include <math.h>

#define XS 512
#define YS 512
#define WDIM 256
#define NCELLS (XS * YS)          // 262144
#define K1_BLOCKS 2048
#define K1_THREADS 256            // 4 waves/block, 32 cells/wave
#define NSLOTS 32                 // atomic sink slots
#define SLOT_STRIDE 16            // u64s per slot stride = 128 B (one cacheline)

typedef float vfloat4 __attribute__((ext_vector_type(4)));

// Kernel 1: per-cell squared L2 distance; batched-butterfly argmin.
// Body identical to Round 1-3 (measured neutral vs serial chain — DS ops are
// not the bottleneck). THIS round's single change: the sink. Instead of 2048
// device-scope atomicMin to ONE address (suspected 60-150us serialized tail,
// since equal-work blocks retire in a burst), blocks hash into 32 slots
// strided one cacheline apart => 64x less same-address contention, spread
// across L2 channels.
__global__ __launch_bounds__(K1_THREADS) void som_dist_kernel(
    const float* __restrict__ x,
    const float* __restrict__ W,
    unsigned long long* __restrict__ ws) {
  const int lane = threadIdx.x & 63;
  const int waveInBlock = threadIdx.x >> 6;
  const int gw = blockIdx.x * (K1_THREADS / 64) + waveInBlock;

  const vfloat4 xv = ((const vfloat4*)x)[lane];

  float bestD = 3.4e38f;
  int bestI = 0;

  const int base = gw * 32;  // 32 consecutive cells per wave
  const int r3 = lane & 3;   // which cell of each batch this lane ends up owning

#pragma unroll 2
  for (int b = 0; b < 8; ++b) {
    const int cb = base + b * 4;
    const vfloat4* row = (const vfloat4*)(W + (size_t)cb * WDIM) + lane;
    // 4 independent coalesced 1 KB row reads (64 lanes x 16 B each)
    const vfloat4 w0 = row[0 * (WDIM / 4)];
    const vfloat4 w1 = row[1 * (WDIM / 4)];
    const vfloat4 w2 = row[2 * (WDIM / 4)];
    const vfloat4 w3 = row[3 * (WDIM / 4)];

    float d;
    float s0, s1, s2, s3;
    d = xv.x - w0.x; s0  = d * d;
    d = xv.y - w0.y; s0 += d * d;
    d = xv.z - w0.z; s0 += d * d;
    d = xv.w - w0.w; s0 += d * d;

    d = xv.x - w1.x; s1  = d * d;
    d = xv.y - w1.y; s1 += d * d;
    d = xv.z - w1.z; s1 += d * d;
    d = xv.w - w1.w; s1 += d * d;

    d = xv.x - w2.x; s2  = d * d;
    d = xv.y - w2.y; s2 += d * d;
    d = xv.z - w2.z; s2 += d * d;
    d = xv.w - w2.w; s2 += d * d;

    d = xv.x - w3.x; s3  = d * d;
    d = xv.y - w3.y; s3 += d * d;
    d = xv.z - w3.z; s3 += d * d;
    d = xv.w - w3.w; s3 += d * d;

    // stage mask=1: (s0,s1) and (s2,s3); lane bit0 picks which cell it keeps
    const bool b0 = (lane & 1) != 0;
    float keepA = b0 ? s1 : s0;
    float sendA = b0 ? s0 : s1;
    float t0 = keepA + __shfl_xor(sendA, 1, 64);   // cell (cb + b0)
    float keepB = b0 ? s3 : s2;
    float sendB = b0 ? s2 : s3;
    float t1 = keepB + __shfl_xor(sendB, 1, 64);   // cell (cb + 2 + b0)

    // stage mask=2: lane bit1 picks t0 vs t1
    const bool b1 = (lane & 2) != 0;
    float keepC = b1 ? t1 : t0;
    float sendC = b1 ? t0 : t1;
    float v = keepC + __shfl_xor(sendC, 2, 64);    // cell (cb + (lane&3)), 1/16 of sum

    // fold the 16 duplicate lane-groups (lane bits 2..5)
    v += __shfl_xor(v, 4, 64);
    v += __shfl_xor(v, 8, 64);
    v += __shfl_xor(v, 16, 64);
    v += __shfl_xor(v, 32, 64);

    // strict < keeps the lowest index on ties within this lane's residue class
    if (v < bestD) { bestD = v; bestI = cb + r3; }
  }

  // fp32 dist (>=0) bit pattern is order-monotone as u32; index in low 32.
  // Packed u64 min => lowest distance, ties broken by lowest index.
  unsigned long long packed =
      ((unsigned long long)__float_as_uint(bestD) << 32) | (unsigned int)bestI;

  // wave-level min across the 64 per-residue candidates
#pragma unroll
  for (int off = 32; off > 0; off >>= 1) {
    const unsigned long long o = __shfl_xor(packed, off, 64);
    packed = (o < packed) ? o : packed;
  }

  __shared__ unsigned long long sbest[K1_THREADS / 64];
  if (lane == 0) sbest[waveInBlock] = packed;
  __syncthreads();
  if (threadIdx.x == 0) {
    unsigned long long m = sbest[0];
#pragma unroll
    for (int i = 1; i < K1_THREADS / 64; ++i) {
      const unsigned long long v2 = sbest[i];
      m = (v2 < m) ? v2 : m;
    }
    // 32 cacheline-strided slots instead of one hot address
    atomicMin(ws + (blockIdx.x & (NSLOTS - 1)) * SLOT_STRIDE, m);
  }
}

// Kernel 2: reduce the 32 slots (L2-hot), write h; block 0 appends wx, wy.
__global__ __launch_bounds__(256) void som_h_kernel(
    const unsigned long long* __restrict__ ws,
    const int* __restrict__ time_step,
    float* __restrict__ out) {
  const int t = threadIdx.x;
  const int lane = t & 63;

  // lanes 0-31 and 32-63 each load all 32 slots; 5-step butterfly within each
  // 32-lane half leaves the global min in EVERY lane.
  unsigned long long v = ws[(lane & (NSLOTS - 1)) * SLOT_STRIDE];
#pragma unroll
  for (int off = 1; off < 32; off <<= 1) {
    const unsigned long long o = __shfl_xor(v, off, 64);
    v = (o < v) ? o : v;
  }

  const int flat = (int)(v & 0xFFFFFFFFULL);
  const int wx = flat >> 9;       // flat / 512
  const int wy = flat & (YS - 1); // flat % 512

  // decay = SIGMA * exp(-t / (1000/ln(SIGMA))), SIGMA = 2
  const float ts = (float)(*time_step);
  const float TIME_CONST = 1442.6950408889634f;  // 1000 / ln(2)
  const float decay = 2.0f * expf(-ts / TIME_CONST);
  const float denom = 2.0f * decay * decay;
  const float inv = -1.0f / denom;

  // h[i][j] = exp(-((i-wx)^2 + (j-wy)^2) / denom); one float4 per thread
  const int e = blockIdx.x * 1024 + t * 4;
  const int i = e >> 9;
  const int j0 = e & (YS - 1);
  const float di = (float)(i - wx);
  const float di2 = di * di;

  const float d0 = (float)(j0 + 0 - wy);
  const float d1 = (float)(j0 + 1 - wy);
  const float d2 = (float)(j0 + 2 - wy);
  const float d3 = (float)(j0 + 3 - wy);
  vfloat4 r;
  r.x = expf((di2 + d0 * d0) * inv);
  r.y = expf((di2 + d1 * d1) * inv);
  r.z = expf((di2 + d2 * d2) * inv);
  r.w = expf((di2 + d3 * d3) * inv);
  ((vfloat4*)out)[e >> 2] = r;

  if (blockIdx.x == 0 && t == 0) {
    out[NCELLS] = (float)wx;      // output order: h, wx, wy
    out[NCELLS + 1] = (float)wy;
  }
}

extern "C" void kernel_launch(void* const* d_in, const int* in_sizes, int n_in,
                              void* d_out, int out_size, void* d_ws, size_t ws_size,
                              hipStream_t stream) {
  const float* x = (const float*)d_in[0];
  const float* W = (const float*)d_in[1];
  const int* ts = (const int*)d_in[2];
  float* out = (float*)d_out;
  unsigned long long* ws = (unsigned long long*)d_ws;

  // Init all 32 strided slots to u64-max so atomicMin never sees poison.
  (void)hipMemsetAsync(ws, 0xFF, NSLOTS * SLOT_STRIDE * 8, stream);
  som_dist_kernel<<<K1_BLOCKS, K1_THREADS, 0, stream>>>(x, W, ws);
  som_h_kernel<<<NCELLS / 1024, 256, 0, stream>>>(ws, ts, out);
}

// Round 5
// 339.238 us; speedup vs baseline: 1.0700x; 1.0688x over previous
//
#include <hip/hip_runtime.h>
#include <math.h>

#define XS 512
#define YS 512
#define WDIM 256
#define NCELLS (XS * YS)          // 262144
#define K1_BLOCKS 2048
#define K1_THREADS 256            // 4 waves/block, 32 cells/wave
#define NSLOTS 32                 // atomic sink slots
#define SLOT_STRIDE 16            // u64s per slot stride = 128 B (one cacheline)

typedef float vfloat4 __attribute__((ext_vector_type(4)));

// Kernel 1: per-cell squared L2 distance, argmin.
// Ledger: serial-shfl+NT = 347.8us; butterfly no-NT = 363.0; +32-slot sink =
// 362.6. Reduction structure and atomic sink are both perf-neutral => the
// stream itself is the knob. Only measured lever so far: nontemporal loads
// (-15us). W is 268MB ~= exactly the 256MiB L3, so allocating reads thrash
// L2+L3 at full victim traffic; NT skips allocation.
// This round: NT restored + 8KB batches with explicit 2-deep prefetch
// pipeline (8-16KB in flight per wave through the reduce phase), butterfly
// extended to 8 cells/batch (10 shuffles per 8KB).
__global__ __launch_bounds__(K1_THREADS) void som_dist_kernel(
    const float* __restrict__ x,
    const float* __restrict__ W,
    unsigned long long* __restrict__ ws) {
  const int lane = threadIdx.x & 63;
  const int waveInBlock = threadIdx.x >> 6;
  const int gw = blockIdx.x * (K1_THREADS / 64) + waveInBlock;

  const vfloat4 xv = ((const vfloat4*)x)[lane];

  float bestD = 3.4e38f;
  int bestI = 0;

  const int base = gw * 32;  // 32 consecutive cells per wave, 4 batches of 8
  const int r7 = lane & 7;   // cell-in-batch this lane owns after the butterfly

  const bool b0 = (lane & 1) != 0;
  const bool b1 = (lane & 2) != 0;
  const bool b2 = (lane & 4) != 0;

  vfloat4 buf[2][8];  // double-buffered row data; all indices static after unroll

  {
    const vfloat4* p0 = (const vfloat4*)(W + (size_t)base * WDIM) + lane;
#pragma unroll
    for (int r = 0; r < 8; ++r)
      buf[0][r] = __builtin_nontemporal_load(p0 + r * (WDIM / 4));
  }

#pragma unroll
  for (int b = 0; b < 4; ++b) {
    // prefetch next 8 rows (8 KB) while reducing the current batch
    if (b < 3) {
      const vfloat4* pn =
          (const vfloat4*)(W + (size_t)(base + (b + 1) * 8) * WDIM) + lane;
#pragma unroll
      for (int r = 0; r < 8; ++r)
        buf[(b + 1) & 1][r] = __builtin_nontemporal_load(pn + r * (WDIM / 4));
    }

    const int cb = base + b * 8;
    float s[8];
#pragma unroll
    for (int r = 0; r < 8; ++r) {
      const vfloat4 wv = buf[b & 1][r];
      const float dx = xv.x - wv.x;
      const float dy = xv.y - wv.y;
      const float dz = xv.z - wv.z;
      const float dw = xv.w - wv.w;
      s[r] = dx * dx + dy * dy + dz * dz + dw * dw;
    }

    // value-halving butterfly: 8 partials -> 1 value/lane, cell = cb + (lane&7)
    // stage mask=1: pairs (0,1)(2,3)(4,5)(6,7); lane bit0 picks kept cell
    float t0, t1, t2, t3;
    {
      float k, sd;
      k = b0 ? s[1] : s[0]; sd = b0 ? s[0] : s[1];
      t0 = k + __shfl_xor(sd, 1, 64);    // cell cb + 0 + b0 (partial over 2 lanes)
      k = b0 ? s[3] : s[2]; sd = b0 ? s[2] : s[3];
      t1 = k + __shfl_xor(sd, 1, 64);    // cell cb + 2 + b0
      k = b0 ? s[5] : s[4]; sd = b0 ? s[4] : s[5];
      t2 = k + __shfl_xor(sd, 1, 64);    // cell cb + 4 + b0
      k = b0 ? s[7] : s[6]; sd = b0 ? s[6] : s[7];
      t3 = k + __shfl_xor(sd, 1, 64);    // cell cb + 6 + b0
    }
    // stage mask=2: lane bit1 picks t-pair member
    float u0, u1;
    {
      float k, sd;
      k = b1 ? t1 : t0; sd = b1 ? t0 : t1;
      u0 = k + __shfl_xor(sd, 2, 64);    // cell cb + 2*b1 + b0
      k = b1 ? t3 : t2; sd = b1 ? t2 : t3;
      u1 = k + __shfl_xor(sd, 2, 64);    // cell cb + 4 + 2*b1 + b0
    }
    // stage mask=4: lane bit2 picks u0 vs u1
    float v;
    {
      const float k = b2 ? u1 : u0;
      const float sd = b2 ? u0 : u1;
      v = k + __shfl_xor(sd, 4, 64);     // cell cb + (lane&7), 1/8 of sum
    }
    // fold the 8 duplicate lane-groups (lane bits 3..5)
    v += __shfl_xor(v, 8, 64);
    v += __shfl_xor(v, 16, 64);
    v += __shfl_xor(v, 32, 64);

    // strict < keeps the lowest index on ties within this lane's residue class
    if (v < bestD) { bestD = v; bestI = cb + r7; }
  }

  // fp32 dist (>=0) bit pattern is order-monotone as u32; index in low 32.
  // Packed u64 min => lowest distance, ties broken by lowest index.
  unsigned long long packed =
      ((unsigned long long)__float_as_uint(bestD) << 32) | (unsigned int)bestI;

  // wave-level min across the 64 per-residue candidates
#pragma unroll
  for (int off = 32; off > 0; off >>= 1) {
    const unsigned long long o = __shfl_xor(packed, off, 64);
    packed = (o < packed) ? o : packed;
  }

  __shared__ unsigned long long sbest[K1_THREADS / 64];
  if (lane == 0) sbest[waveInBlock] = packed;
  __syncthreads();
  if (threadIdx.x == 0) {
    unsigned long long m = sbest[0];
#pragma unroll
    for (int i = 1; i < K1_THREADS / 64; ++i) {
      const unsigned long long v2 = sbest[i];
      m = (v2 < m) ? v2 : m;
    }
    // 32 cacheline-strided slots (measured neutral vs 1 slot, kept: harmless)
    atomicMin(ws + (blockIdx.x & (NSLOTS - 1)) * SLOT_STRIDE, m);
  }
}

// Kernel 2: reduce the 32 slots (L2-hot), write h; block 0 appends wx, wy.
__global__ __launch_bounds__(256) void som_h_kernel(
    const unsigned long long* __restrict__ ws,
    const int* __restrict__ time_step,
    float* __restrict__ out) {
  const int t = threadIdx.x;
  const int lane = t & 63;

  // lanes 0-31 and 32-63 each load all 32 slots; 5-step butterfly within each
  // 32-lane half leaves the global min in EVERY lane.
  unsigned long long v = ws[(lane & (NSLOTS - 1)) * SLOT_STRIDE];
#pragma unroll
  for (int off = 1; off < 32; off <<= 1) {
    const unsigned long long o = __shfl_xor(v, off, 64);
    v = (o < v) ? o : v;
  }

  const int flat = (int)(v & 0xFFFFFFFFULL);
  const int wx = flat >> 9;       // flat / 512
  const int wy = flat & (YS - 1); // flat % 512

  // decay = SIGMA * exp(-t / (1000/ln(SIGMA))), SIGMA = 2
  const float ts = (float)(*time_step);
  const float TIME_CONST = 1442.6950408889634f;  // 1000 / ln(2)
  const float decay = 2.0f * expf(-ts / TIME_CONST);
  const float denom = 2.0f * decay * decay;
  const float inv = -1.0f / denom;

  // h[i][j] = exp(-((i-wx)^2 + (j-wy)^2) / denom); one float4 per thread
  const int e = blockIdx.x * 1024 + t * 4;
  const int i = e >> 9;
  const int j0 = e & (YS - 1);
  const float di = (float)(i - wx);
  const float di2 = di * di;

  const float d0 = (float)(j0 + 0 - wy);
  const float d1 = (float)(j0 + 1 - wy);
  const float d2 = (float)(j0 + 2 - wy);
  const float d3 = (float)(j0 + 3 - wy);
  vfloat4 r;
  r.x = expf((di2 + d0 * d0) * inv);
  r.y = expf((di2 + d1 * d1) * inv);
  r.z = expf((di2 + d2 * d2) * inv);
  r.w = expf((di2 + d3 * d3) * inv);
  ((vfloat4*)out)[e >> 2] = r;

  if (blockIdx.x == 0 && t == 0) {
    out[NCELLS] = (float)wx;      // output order: h, wx, wy
    out[NCELLS + 1] = (float)wy;
  }
}

extern "C" void kernel_launch(void* const* d_in, const int* in_sizes, int n_in,
                              void* d_out, int out_size, void* d_ws, size_t ws_size,
                              hipStream_t stream) {
  const float* x = (const float*)d_in[0];
  const float* W = (const float*)d_in[1];
  const int* ts = (const int*)d_in[2];
  float* out = (float*)d_out;
  unsigned long long* ws = (unsigned long long*)d_ws;

  // Init all 32 strided slots to u64-max so atomicMin never sees poison.
  (void)hipMemsetAsync(ws, 0xFF, NSLOTS * SLOT_STRIDE * 8, stream);
  som_dist_kernel<<<K1_BLOCKS, K1_THREADS, 0, stream>>>(x, W, ws);
  som_h_kernel<<<NCELLS / 1024, 256, 0, stream>>>(ws, ts, out);
}